// Round 1
// baseline (31086.218 us; speedup 1.0000x reference)
//
#include <hip/hip_runtime.h>

#define HDIM   2048
#define TUNEDC 10
#define BATCH  16
#define TSTEPS 1024
#define NINP   8
#define NOUTP  8
#define RPW    8                 // rows of Wm per workgroup
#define NWG    (HDIM / RPW)      // 256 workgroups
#define NTHR   256

#define DT_C   0.001f
#define TAU_C  0.01f
#define PREL_C 1.0f
#define BETA_C 1.5f

// workspace layout (floats)
#define VBUF_OFF 1024
#define VBUF_SZ  (BATCH * HDIM)  // 32768 floats per buffer, two buffers

// LDS layout (floats)
#define LDS_W      0
#define SCR_STRIDE 140                         // padded (x4-aligned, 2-way-max banks)
#define LDS_SCR    (RPW * HDIM)                // 16384
#define LDS_YH     (LDS_SCR + 128 * SCR_STRIDE)
#define LDS_WIH    (LDS_YH + 256)
#define LDS_TOTAL  (LDS_WIH + RPW * NINP)      // 34624 floats = 138496 B

extern "C" __global__ __launch_bounds__(NTHR, 1)
void rnn_main(const float* __restrict__ x, const float* __restrict__ h0,
              const float* __restrict__ Wih, const float* __restrict__ Wt,
              const float* __restrict__ Wf, const float* __restrict__ Wmask,
              const float* __restrict__ tau_d,
              float* __restrict__ h_out, float* __restrict__ r_out,
              int* flags, float* vbuf)
{
    extern __shared__ float smem[];
    float* Wl  = smem + LDS_W;    // [8][2048] masked recurrent rows (fp32)
    float* scr = smem + LDS_SCR;  // [128][SCR_STRIDE] transpose-reduction scratch
    float* yh  = smem + LDS_YH;   // [128][2] half-sums
    float* wih = smem + LDS_WIH;  // [8][8]

    const int wg   = blockIdx.x;
    const int tid  = threadIdx.x;
    const int lane = tid & 63;
    const int w    = tid >> 6;    // wave 0..3
    const int r0   = wg * RPW;

    // ---- stage masked recurrent weight slice: Wm[r][j] = mask * concat(tuned,fixed) ----
    for (int idx = tid; idx < RPW * HDIM; idx += NTHR) {
        int rl = idx >> 11;
        int j  = idx & (HDIM - 1);
        int r  = r0 + rl;
        float base = (j < TUNEDC) ? Wt[r * TUNEDC + j]
                                  : Wf[r * (HDIM - TUNEDC) + (j - TUNEDC)];
        Wl[idx] = Wmask[(size_t)r * HDIM + j] * base;
    }
    if (tid < RPW * NINP) {
        int rl = tid >> 3, k = tid & 7;
        wih[tid] = Wih[(r0 + rl) * NINP + k];
    }

    // ---- owner threads (128): state (h,r,tanh h) lives in registers ----
    float h_s = 0.f, r_s = PREL_C, hT_s = 0.f, itau_s = 1.f;
    int ob = 0, orl = 0, oro = 0;
    const bool owner = (tid < BATCH * RPW);
    if (owner) {
        ob  = tid >> 3;            // batch
        orl = tid & 7;             // local row
        oro = r0 + orl;            // global row
        h_s = h0[ob * HDIM + oro];
        hT_s = tanhf(h_s);
        itau_s = 1.0f / tau_d[oro];
        vbuf[ob * HDIM + oro] = r_s * hT_s;       // publish v_0 into buffer 0
    }
    __syncthreads();
    __builtin_amdgcn_fence(__ATOMIC_RELEASE, "agent");
    __syncthreads();
    if (tid == 0)
        __hip_atomic_store(&flags[wg], 1, __ATOMIC_RELAXED, __HIP_MEMORY_SCOPE_AGENT);

    const int bg = w & 1;   // batch group: batches 8*bg .. 8*bg+7
    const int kh = w >> 1;  // k half

    for (int t = 0; t < TSTEPS; ++t) {
        // ---- wait until every WG published its slice of v_t ----
        const int target = t + 1;
        while (!__syncthreads_and(
                   (int)(__hip_atomic_load(&flags[tid], __ATOMIC_RELAXED,
                                           __HIP_MEMORY_SCOPE_AGENT) >= target))) {
            __builtin_amdgcn_s_sleep(1);
        }
        __builtin_amdgcn_fence(__ATOMIC_ACQUIRE, "agent");

        const float4* vc  = (const float4*)(vbuf + (t & 1) * VBUF_SZ);
        const float4* wl4 = (const float4*)Wl;

        // ---- y[8 rows][16 batches] = W_slice @ v ; acc tile 8x8 per thread ----
        float acc[RPW][8];
        #pragma unroll
        for (int rl = 0; rl < RPW; ++rl)
            #pragma unroll
            for (int bl = 0; bl < 8; ++bl) acc[rl][bl] = 0.f;

        #pragma unroll
        for (int jj = 0; jj < 4; ++jj) {
            const int k4 = lane + 64 * kh + 128 * jj;   // float4 index into row
            float4 vv[8];
            #pragma unroll
            for (int bl = 0; bl < 8; ++bl)
                vv[bl] = vc[(8 * bg + bl) * (HDIM / 4) + k4];
            #pragma unroll
            for (int rl = 0; rl < RPW; ++rl) {
                float4 wv = wl4[rl * (HDIM / 4) + k4];
                #pragma unroll
                for (int bl = 0; bl < 8; ++bl) {
                    acc[rl][bl] = fmaf(wv.x, vv[bl].x, acc[rl][bl]);
                    acc[rl][bl] = fmaf(wv.y, vv[bl].y, acc[rl][bl]);
                    acc[rl][bl] = fmaf(wv.z, vv[bl].z, acc[rl][bl]);
                    acc[rl][bl] = fmaf(wv.w, vv[bl].w, acc[rl][bl]);
                }
            }
        }

        // ---- transpose-reduce over the 128 k-splits via LDS ----
        {
            const int ks = kh * 64 + lane;
            #pragma unroll
            for (int rl = 0; rl < RPW; ++rl)
                #pragma unroll
                for (int bl = 0; bl < 8; ++bl) {
                    int p = (8 * bg + bl) * 8 + rl;     // pair = b*8 + rl
                    scr[p * SCR_STRIDE + ks] = acc[rl][bl];
                }
        }
        __syncthreads();
        {
            const int p  = tid & 127;
            const int hh = tid >> 7;
            const float4* s4 = (const float4*)(scr + p * SCR_STRIDE + hh * 64);
            float s = 0.f;
            #pragma unroll
            for (int i = 0; i < 16; ++i) {
                float4 q = s4[i];
                s += q.x + q.y + q.z + q.w;
            }
            yh[p * 2 + hh] = s;
        }
        __syncthreads();

        // ---- owner integrates state, writes outputs, publishes next v ----
        if (owner) {
            float y = yh[tid * 2] + yh[tid * 2 + 1];
            const float* xt = x + ((size_t)ob * TSTEPS + t) * NINP;
            float xin = 0.f;
            #pragma unroll
            for (int k = 0; k < NINP; ++k)
                xin = fmaf(xt[k], wih[orl * NINP + k], xin);
            // dh = (-h + rec + xin)/TAU ; h' = h + dh*DT   (W_zh term is exactly 0)
            float dh = (y + xin - h_s) * (1.0f / TAU_C);
            float hn = fmaf(dh, DT_C, h_s);
            // r' = r + ((1-r)/tau_depr - 1.5*r*tanh(h))*DT   (uses previous tanh h)
            float rn = r_s + ((PREL_C - r_s) * itau_s - BETA_C * r_s * hT_s) * DT_C;
            float hTn = tanhf(hn);
            size_t oidx = ((size_t)ob * TSTEPS + t) * HDIM + oro;
            h_out[oidx] = hn;
            r_out[oidx] = rn;
            h_s = hn; r_s = rn; hT_s = hTn;
            if (t + 1 < TSTEPS) {
                float* vn = vbuf + ((t + 1) & 1) * VBUF_SZ;
                vn[ob * HDIM + oro] = r_s * hT_s;   // v_{t+1}
            }
        }
        if (t + 1 < TSTEPS) {
            __syncthreads();
            __builtin_amdgcn_fence(__ATOMIC_RELEASE, "agent");
            __syncthreads();
            if (tid == 0)
                __hip_atomic_store(&flags[wg], t + 2, __ATOMIC_RELAXED,
                                   __HIP_MEMORY_SCOPE_AGENT);
        }
    }
}

// z[b,t,:] = tanh(h[b,t,:]) @ W_hz.T — decoupled post-pass, one block per (b,t)
extern "C" __global__ __launch_bounds__(256, 2)
void z_kernel(const float* __restrict__ h_out, const float* __restrict__ Whz,
              float* __restrict__ z_out)
{
    const int bt  = blockIdx.x;
    const int tid = threadIdx.x;
    const float4* hp = (const float4*)(h_out + (size_t)bt * HDIM);
    float4 a = hp[tid * 2], b4 = hp[tid * 2 + 1];
    float th[8] = { tanhf(a.x),  tanhf(a.y),  tanhf(a.z),  tanhf(a.w),
                    tanhf(b4.x), tanhf(b4.y), tanhf(b4.z), tanhf(b4.w) };
    float acc[NOUTP];
    #pragma unroll
    for (int o = 0; o < NOUTP; ++o) {
        const float4* wp = (const float4*)(Whz + o * HDIM);
        float4 wa = wp[tid * 2], wb = wp[tid * 2 + 1];
        acc[o] = th[0]*wa.x + th[1]*wa.y + th[2]*wa.z + th[3]*wa.w
               + th[4]*wb.x + th[5]*wb.y + th[6]*wb.z + th[7]*wb.w;
    }
    #pragma unroll
    for (int off = 32; off > 0; off >>= 1)
        #pragma unroll
        for (int o = 0; o < NOUTP; ++o)
            acc[o] += __shfl_down(acc[o], off, 64);
    __shared__ float part[4][NOUTP];
    if ((tid & 63) == 0)
        for (int o = 0; o < NOUTP; ++o) part[tid >> 6][o] = acc[o];
    __syncthreads();
    if (tid < NOUTP)
        z_out[(size_t)bt * NOUTP + tid] =
            part[0][tid] + part[1][tid] + part[2][tid] + part[3][tid];
}

extern "C" void kernel_launch(void* const* d_in, const int* in_sizes, int n_in,
                              void* d_out, int out_size, void* d_ws, size_t ws_size,
                              hipStream_t stream)
{
    (void)in_sizes; (void)n_in; (void)out_size; (void)ws_size;
    const float* x    = (const float*)d_in[0];
    const float* h0   = (const float*)d_in[1];
    const float* Wih  = (const float*)d_in[2];
    const float* Wt   = (const float*)d_in[3];
    const float* Wf   = (const float*)d_in[4];
    const float* Wm   = (const float*)d_in[5];
    const float* Whz  = (const float*)d_in[6];
    // d_in[7] = W_zh: all zeros (echo_state=False) -> its term is exactly 0, skipped.
    const float* taud = (const float*)d_in[8];

    float* z_out = (float*)d_out;
    float* h_out = z_out + (size_t)BATCH * TSTEPS * NOUTP;
    float* r_out = h_out + (size_t)BATCH * TSTEPS * HDIM;

    int*   flags = (int*)d_ws;
    float* vbuf  = (float*)d_ws + VBUF_OFF;

    hipFuncSetAttribute((const void*)rnn_main,
                        hipFuncAttributeMaxDynamicSharedMemorySize,
                        LDS_TOTAL * (int)sizeof(float));

    hipMemsetAsync(flags, 0, NWG * sizeof(int), stream);
    rnn_main<<<NWG, NTHR, LDS_TOTAL * sizeof(float), stream>>>(
        x, h0, Wih, Wt, Wf, Wm, taud, h_out, r_out, flags, vbuf);
    z_kernel<<<BATCH * TSTEPS, 256, 0, stream>>>(h_out, Whz, z_out);
}

// Round 2
// 9135.361 us; speedup vs baseline: 3.4028x; 3.4028x over previous
//
#include <hip/hip_runtime.h>

#define HDIM   2048
#define TUNEDC 10
#define BATCH  16
#define TSTEPS 1024
#define NINP   8
#define NOUTP  8
#define RPW    8                 // rows of Wm per workgroup
#define NWG    (HDIM / RPW)      // 256 workgroups
#define NTHR   256

#define DT_C   0.001f
#define TAU_C  0.01f
#define PREL_C 1.0f
#define BETA_C 1.5f

// workspace layout (floats)
#define VBUF_OFF 1024
#define VBUF_SZ  (BATCH * HDIM)  // 32768 floats per buffer, two buffers

// LDS layout (floats)
#define LDS_W      0
#define SCR_STRIDE 140
#define LDS_SCR    (RPW * HDIM)                // 16384
#define LDS_YH     (LDS_SCR + 128 * SCR_STRIDE)
#define LDS_WIH    (LDS_YH + 256)
#define LDS_TOTAL  (LDS_WIH + RPW * NINP)      // 34624 floats = 138496 B

#define AGENT __HIP_MEMORY_SCOPE_AGENT

extern "C" __global__ __launch_bounds__(NTHR, 1)
void rnn_main(const float* __restrict__ x, const float* __restrict__ h0,
              const float* __restrict__ Wih, const float* __restrict__ Wt,
              const float* __restrict__ Wf, const float* __restrict__ Wmask,
              const float* __restrict__ tau_d,
              float* __restrict__ h_out, float* __restrict__ r_out,
              int* ctr, float* vbuf)
{
    extern __shared__ float smem[];
    float* Wl  = smem + LDS_W;    // [8][2048] masked recurrent rows (fp32)
    float* scr = smem + LDS_SCR;  // [128][SCR_STRIDE] transpose-reduction scratch
    float* yh  = smem + LDS_YH;   // [128][2] half-sums
    float* wih = smem + LDS_WIH;  // [8][8]

    const int wg   = blockIdx.x;
    const int tid  = threadIdx.x;
    const int lane = tid & 63;
    const int w    = tid >> 6;    // wave 0..3
    const int r0   = wg * RPW;

    // ---- stage masked recurrent weight slice: Wm[r][j] = mask * concat(tuned,fixed) ----
    for (int idx = tid; idx < RPW * HDIM; idx += NTHR) {
        int rl = idx >> 11;
        int j  = idx & (HDIM - 1);
        int r  = r0 + rl;
        float base = (j < TUNEDC) ? Wt[r * TUNEDC + j]
                                  : Wf[r * (HDIM - TUNEDC) + (j - TUNEDC)];
        Wl[idx] = Wmask[(size_t)r * HDIM + j] * base;
    }
    if (tid < RPW * NINP) {
        int rl = tid >> 3, k = tid & 7;
        wih[tid] = Wih[(r0 + rl) * NINP + k];
    }

    // ---- owner threads (128): state (h,r,tanh h) lives in registers ----
    float h_s = 0.f, r_s = PREL_C, hT_s = 0.f, itau_s = 1.f;
    int ob = 0, orl = 0, oro = 0;
    const bool owner = (tid < BATCH * RPW);
    if (owner) {
        ob  = tid >> 3;            // batch
        orl = tid & 7;             // local row
        oro = r0 + orl;            // global row
        h_s = h0[ob * HDIM + oro];
        hT_s = tanhf(h_s);
        itau_s = 1.0f / tau_d[oro];
        // publish v_0 into buffer 0: coherent (write-through to MALL), no fence
        __hip_atomic_store(&vbuf[ob * HDIM + oro], r_s * hT_s,
                           __ATOMIC_RELAXED, AGENT);
    }
    // __syncthreads drains vmcnt(0) (documented s_waitcnt before s_barrier):
    // all v_0 stores are globally visible before the counter add below.
    __builtin_amdgcn_fence(__ATOMIC_RELEASE, "workgroup");  // vmcnt drain, no cache flush
    __syncthreads();
    if (tid == 0)
        __hip_atomic_fetch_add(ctr, 1, __ATOMIC_RELAXED, AGENT);

    const int bg = w & 1;   // batch group: batches 8*bg .. 8*bg+7
    const int kh = w >> 1;  // k half

    for (int t = 0; t < TSTEPS; ++t) {
        // ---- single-counter barrier: all WGs published v_t ----
        if (tid == 0) {
            const int target = NWG * (t + 1);
            while (__hip_atomic_load(ctr, __ATOMIC_RELAXED, AGENT) < target)
                __builtin_amdgcn_s_sleep(1);
        }
        __syncthreads();

        const float* vc = vbuf + (t & 1) * VBUF_SZ;

        // ---- y[8 rows][16 batches] = W_slice @ v ; acc tile 8x8 per thread ----
        float acc[RPW][8];
        #pragma unroll
        for (int rl = 0; rl < RPW; ++rl)
            #pragma unroll
            for (int bl = 0; bl < 8; ++bl) acc[rl][bl] = 0.f;

        #pragma unroll
        for (int jj = 0; jj < 16; ++jj) {
            const int k = kh * 1024 + jj * 64 + lane;  // lane-consecutive dwords
            float vv[8];
            #pragma unroll
            for (int bl = 0; bl < 8; ++bl)
                vv[bl] = __hip_atomic_load(&vc[(8 * bg + bl) * HDIM + k],
                                           __ATOMIC_RELAXED, AGENT);
            #pragma unroll
            for (int rl = 0; rl < RPW; ++rl) {
                float wv = Wl[rl * HDIM + k];
                #pragma unroll
                for (int bl = 0; bl < 8; ++bl)
                    acc[rl][bl] = fmaf(wv, vv[bl], acc[rl][bl]);
            }
        }

        // ---- transpose-reduce over the 128 k-splits via LDS ----
        {
            const int ks = kh * 64 + lane;
            #pragma unroll
            for (int rl = 0; rl < RPW; ++rl)
                #pragma unroll
                for (int bl = 0; bl < 8; ++bl) {
                    int p = (8 * bg + bl) * 8 + rl;     // pair = b*8 + rl
                    scr[p * SCR_STRIDE + ks] = acc[rl][bl];
                }
        }
        __syncthreads();
        {
            const int p  = tid & 127;
            const int hh = tid >> 7;
            const float4* s4 = (const float4*)(scr + p * SCR_STRIDE + hh * 64);
            float s = 0.f;
            #pragma unroll
            for (int i = 0; i < 16; ++i) {
                float4 q = s4[i];
                s += q.x + q.y + q.z + q.w;
            }
            yh[p * 2 + hh] = s;
        }
        __syncthreads();

        // ---- owner integrates state, writes outputs, publishes next v ----
        if (owner) {
            float y = yh[tid * 2] + yh[tid * 2 + 1];
            const float* xt = x + ((size_t)ob * TSTEPS + t) * NINP;
            float xin = 0.f;
            #pragma unroll
            for (int k = 0; k < NINP; ++k)
                xin = fmaf(xt[k], wih[orl * NINP + k], xin);
            // dh = (-h + rec + xin)/TAU ; h' = h + dh*DT   (W_zh term is exactly 0)
            float dh = (y + xin - h_s) * (1.0f / TAU_C);
            float hn = fmaf(dh, DT_C, h_s);
            // r' = r + ((1-r)/tau_depr - 1.5*r*tanh(h))*DT  (uses previous tanh h)
            float rn = r_s + ((PREL_C - r_s) * itau_s - BETA_C * r_s * hT_s) * DT_C;
            float hTn = tanhf(hn);
            size_t oidx = ((size_t)ob * TSTEPS + t) * HDIM + oro;
            h_out[oidx] = hn;
            r_out[oidx] = rn;
            h_s = hn; r_s = rn; hT_s = hTn;
            if (t + 1 < TSTEPS) {
                float* vn = vbuf + ((t + 1) & 1) * VBUF_SZ;
                __hip_atomic_store(&vn[ob * HDIM + oro], r_s * hT_s,
                                   __ATOMIC_RELAXED, AGENT);
            }
        }
        if (t + 1 < TSTEPS) {
            // drain THIS WG's v stores (and v loads of buffer t&1, so nobody can
            // overwrite a buffer we're still reading) before counting ourselves in.
            __builtin_amdgcn_fence(__ATOMIC_RELEASE, "workgroup");
            __syncthreads();
            if (tid == 0)
                __hip_atomic_fetch_add(ctr, 1, __ATOMIC_RELAXED, AGENT);
        }
    }
}

// z[b,t,:] = tanh(h[b,t,:]) @ W_hz.T — decoupled post-pass, one block per (b,t)
extern "C" __global__ __launch_bounds__(256, 2)
void z_kernel(const float* __restrict__ h_out, const float* __restrict__ Whz,
              float* __restrict__ z_out)
{
    const int bt  = blockIdx.x;
    const int tid = threadIdx.x;
    const float4* hp = (const float4*)(h_out + (size_t)bt * HDIM);
    float4 a = hp[tid * 2], b4 = hp[tid * 2 + 1];
    float th[8] = { tanhf(a.x),  tanhf(a.y),  tanhf(a.z),  tanhf(a.w),
                    tanhf(b4.x), tanhf(b4.y), tanhf(b4.z), tanhf(b4.w) };
    float acc[NOUTP];
    #pragma unroll
    for (int o = 0; o < NOUTP; ++o) {
        const float4* wp = (const float4*)(Whz + o * HDIM);
        float4 wa = wp[tid * 2], wb = wp[tid * 2 + 1];
        acc[o] = th[0]*wa.x + th[1]*wa.y + th[2]*wa.z + th[3]*wa.w
               + th[4]*wb.x + th[5]*wb.y + th[6]*wb.z + th[7]*wb.w;
    }
    #pragma unroll
    for (int off = 32; off > 0; off >>= 1)
        #pragma unroll
        for (int o = 0; o < NOUTP; ++o)
            acc[o] += __shfl_down(acc[o], off, 64);
    __shared__ float part[4][NOUTP];
    if ((tid & 63) == 0)
        for (int o = 0; o < NOUTP; ++o) part[tid >> 6][o] = acc[o];
    __syncthreads();
    if (tid < NOUTP)
        z_out[(size_t)bt * NOUTP + tid] =
            part[0][tid] + part[1][tid] + part[2][tid] + part[3][tid];
}

extern "C" void kernel_launch(void* const* d_in, const int* in_sizes, int n_in,
                              void* d_out, int out_size, void* d_ws, size_t ws_size,
                              hipStream_t stream)
{
    (void)in_sizes; (void)n_in; (void)out_size; (void)ws_size;
    const float* x    = (const float*)d_in[0];
    const float* h0   = (const float*)d_in[1];
    const float* Wih  = (const float*)d_in[2];
    const float* Wt   = (const float*)d_in[3];
    const float* Wf   = (const float*)d_in[4];
    const float* Wm   = (const float*)d_in[5];
    const float* Whz  = (const float*)d_in[6];
    // d_in[7] = W_zh: all zeros (echo_state=False) -> its term is exactly 0, skipped.
    const float* taud = (const float*)d_in[8];

    float* z_out = (float*)d_out;
    float* h_out = z_out + (size_t)BATCH * TSTEPS * NOUTP;
    float* r_out = h_out + (size_t)BATCH * TSTEPS * HDIM;

    int*   ctr  = (int*)d_ws;
    float* vbuf = (float*)d_ws + VBUF_OFF;

    hipFuncSetAttribute((const void*)rnn_main,
                        hipFuncAttributeMaxDynamicSharedMemorySize,
                        LDS_TOTAL * (int)sizeof(float));

    hipMemsetAsync(ctr, 0, 256 * sizeof(int), stream);
    rnn_main<<<NWG, NTHR, LDS_TOTAL * sizeof(float), stream>>>(
        x, h0, Wih, Wt, Wf, Wm, taud, h_out, r_out, ctr, vbuf);
    z_kernel<<<BATCH * TSTEPS, 256, 0, stream>>>(h_out, Whz, z_out);
}